// Round 8
// baseline (462.201 us; speedup 1.0000x reference)
//
#include <hip/hip_runtime.h>
#include <hip/hip_bf16.h>
#include <math.h>

#define HN 8
#define DM 512
#define DHD 64
#define FFD 2048
#define BB 2
#define SS 4096
#define MT (BB*SS)   // 8192 token rows

typedef __bf16 bf16_t;
typedef __bf16 bf16x8 __attribute__((ext_vector_type(8)));
typedef __bf16 bf16x4 __attribute__((ext_vector_type(4)));
typedef float  floatx4 __attribute__((ext_vector_type(4)));

// Async global->LDS. NOTE (m104/m108): LDS dest is wave-uniform base + lane*16;
// all swizzling must be applied on the GLOBAL SOURCE side, LDS dest stays linear.
__device__ __forceinline__ void async_copy16(const bf16_t* g, bf16_t* l) {
  __builtin_amdgcn_global_load_lds((const __attribute__((address_space(1))) void*)g,
                                   (__attribute__((address_space(3))) void*)l,
                                   16, 0, 0);
}

__device__ __forceinline__ float gelu_f(float x) {
  return 0.5f * x * (1.0f + erff(x * 0.70710678118654752f));
}

#if __has_builtin(__builtin_amdgcn_exp2f)
__device__ __forceinline__ float fast_exp2(float x) { return __builtin_amdgcn_exp2f(x); }
#else
__device__ __forceinline__ float fast_exp2(float x) { return __expf(x * 0.69314718056f); }
#endif

// ---------------- LayerNorm: fp32 in -> bf16 out, fused gamma/beta ----------
__global__ __launch_bounds__(256)
void ln_kernel(const float* __restrict__ x, const float* __restrict__ g,
               const float* __restrict__ be, bf16_t* __restrict__ out)
{
  const int row = blockIdx.x, t = threadIdx.x;
  const float* xr = x + (size_t)row * DM;
  float v0 = xr[t], v1 = xr[t + 256];
  float s = v0 + v1, s2 = v0 * v0 + v1 * v1;
#pragma unroll
  for (int o = 32; o > 0; o >>= 1) { s += __shfl_down(s, o); s2 += __shfl_down(s2, o); }
  __shared__ float red[8];
  if ((t & 63) == 0) { red[(t >> 6) * 2] = s; red[(t >> 6) * 2 + 1] = s2; }
  __syncthreads();
  float ts  = red[0] + red[2] + red[4] + red[6];
  float ts2 = red[1] + red[3] + red[5] + red[7];
  float mu = ts * (1.0f / DM);
  float rv = rsqrtf(ts2 * (1.0f / DM) - mu * mu + 1e-5f);
  out[(size_t)row * DM + t]       = (bf16_t)((v0 - mu) * rv * g[t]       + be[t]);
  out[(size_t)row * DM + t + 256] = (bf16_t)((v1 - mu) * rv * g[t + 256] + be[t + 256]);
}

// ------------- Fused weight prep: all 6 transposes in one launch ------------
__global__ __launch_bounds__(256)
void prep_weights(const float* __restrict__ Wq, const float* __restrict__ Wk,
                  const float* __restrict__ Wv, const float* __restrict__ Wo,
                  const float* __restrict__ W1, const float* __restrict__ W2,
                  bf16_t* __restrict__ WqkvT, bf16_t* __restrict__ WoT,
                  bf16_t* __restrict__ W1T, bf16_t* __restrict__ W2T)
{
  const int bid = blockIdx.x;
  const float* src; bf16_t* dst; int Kd, Nd, n0, k0;
  if (bid < 768) {
    int seg = bid >> 8, t = bid & 255;
    src = (seg == 0) ? Wq : (seg == 1) ? Wk : Wv;
    dst = WqkvT + (size_t)seg * 512 * 512;
    Kd = 512; Nd = 512; n0 = (t & 15) * 32; k0 = (t >> 4) * 32;
  } else if (bid < 1024) {
    int t = bid - 768; src = Wo; dst = WoT;
    Kd = 512; Nd = 512; n0 = (t & 15) * 32; k0 = (t >> 4) * 32;
  } else if (bid < 2048) {
    int t = bid - 1024; src = W1; dst = W1T;
    Kd = 512; Nd = 2048; n0 = (t & 63) * 32; k0 = (t >> 6) * 32;
  } else {
    int t = bid - 2048; src = W2; dst = W2T;
    Kd = 2048; Nd = 512; n0 = (t & 15) * 32; k0 = (t >> 4) * 32;
  }
  __shared__ float tile[32][33];
  const int tx = threadIdx.x & 31, ty = threadIdx.x >> 5;
#pragma unroll
  for (int i = 0; i < 32; i += 8)
    tile[ty + i][tx] = src[(size_t)(k0 + ty + i) * Nd + n0 + tx];
  __syncthreads();
#pragma unroll
  for (int i = 0; i < 32; i += 8)
    dst[(size_t)(n0 + ty + i) * Kd + k0 + tx] = (bf16_t)tile[tx][ty + i];
}

// ---------------- GEMM: C[M,N] = A[M,K] * Bt[N,K]^T, bf16 MFMA --------------
// Tile = (32*MI) x (32*NJ), BK=64, 4 waves in 2x2; wave computes MI x NJ
// 16x16 output blocks. Staging: linear LDS dest, source chunk XOR row&7.
// EPI: 2 = f32 gelu(acc+bias)+res; 3 = bf16 gelu(acc+bias); 4 = f32 acc+bias+res
//      5 = fused-QKV epilogue (q scaled, k row-major, v transposed+sigma-permuted)
template <int MI, int NJ, int EPI>
__global__ __launch_bounds__(256)
void gemm_bt(const bf16_t* __restrict__ A, const bf16_t* __restrict__ Bt,
             const int M, const int N, const int K,
             const float* __restrict__ bias, const float* __restrict__ res,
             bf16_t* __restrict__ outb, float* __restrict__ outf,
             bf16_t* __restrict__ out2, bf16_t* __restrict__ out3, const int ldt)
{
  constexpr int MTILE = 32 * MI, NTILE = 32 * NJ;
  constexpr int ACOPY = MTILE / 32;    // staging instrs per thread (BK=64)
  constexpr int BCOPY = NTILE / 32;
  __shared__ __align__(16) bf16_t lA[MTILE * 64];
  __shared__ __align__(16) bf16_t lB[NTILE * 64];
  const int tid = threadIdx.x;
  const int wave = tid >> 6, lane = tid & 63;
  const int wm = wave & 1, wn = wave >> 1;
  const int quad = lane >> 4, l16 = lane & 15;

  int srA[ACOPY > BCOPY ? ACOPY : BCOPY], scA[ACOPY > BCOPY ? ACOPY : BCOPY];
#pragma unroll
  for (int i = 0; i < (ACOPY > BCOPY ? ACOPY : BCOPY); ++i) {
    int flat = tid + 256 * i;
    int r = flat >> 3, ch = flat & 7;
    srA[i] = r;
    scA[i] = (ch ^ (r & 7)) * 8;       // source-side swizzle, dest stays linear
  }
  const bf16_t* Ab = A + (size_t)(blockIdx.x * MTILE) * K;
  const bf16_t* Bb = Bt + (size_t)(blockIdx.y * NTILE) * K;

  const floatx4 vzero = {0.f, 0.f, 0.f, 0.f};
  floatx4 acc[MI][NJ];
#pragma unroll
  for (int i = 0; i < MI; ++i)
#pragma unroll
    for (int j = 0; j < NJ; ++j) acc[i][j] = vzero;

  for (int k0 = 0; k0 < K; k0 += 64) {
    __syncthreads();
#pragma unroll
    for (int i = 0; i < ACOPY; ++i)
      async_copy16(Ab + (size_t)srA[i] * K + k0 + scA[i], lA + (tid + 256 * i) * 8);
#pragma unroll
    for (int i = 0; i < BCOPY; ++i)
      async_copy16(Bb + (size_t)srA[i] * K + k0 + scA[i], lB + (tid + 256 * i) * 8);
    __syncthreads();
#pragma unroll
    for (int c = 0; c < 2; ++c) {
      bf16x8 af[MI], bfv[NJ];
#pragma unroll
      for (int i = 0; i < MI; ++i)
        af[i] = *(const bf16x8*)(lA + (wm * 16 * MI + i * 16 + l16) * 64
                                 + (((c * 4 + quad) ^ (l16 & 7)) * 8));
#pragma unroll
      for (int j = 0; j < NJ; ++j)
        bfv[j] = *(const bf16x8*)(lB + (wn * 16 * NJ + j * 16 + l16) * 64
                                  + (((c * 4 + quad) ^ (l16 & 7)) * 8));
#pragma unroll
      for (int i = 0; i < MI; ++i)
#pragma unroll
        for (int j = 0; j < NJ; ++j)
          acc[i][j] = __builtin_amdgcn_mfma_f32_16x16x32_bf16(af[i], bfv[j], acc[i][j], 0, 0, 0);
    }
  }

  const int m00 = blockIdx.x * MTILE + wm * 16 * MI;
  const int n00 = blockIdx.y * NTILE + wn * 16 * NJ;
#pragma unroll
  for (int i = 0; i < MI; ++i) {
#pragma unroll
    for (int j = 0; j < NJ; ++j) {
      const int m0 = m00 + i * 16 + quad * 4;     // C/D: row=quad*4+reg, col=l16
      const int n  = n00 + j * 16 + l16;
      floatx4 v = acc[i][j];
      if (EPI == 2) {
        const float bb = bias[n];
#pragma unroll
        for (int r = 0; r < 4; ++r)
          outf[(size_t)(m0 + r) * N + n] = gelu_f(v[r] + bb) + res[(size_t)(m0 + r) * N + n];
      } else if (EPI == 3) {
        const float bb = bias[n];
#pragma unroll
        for (int r = 0; r < 4; ++r)
          outb[(size_t)(m0 + r) * N + n] = (bf16_t)gelu_f(v[r] + bb);
      } else if (EPI == 4) {
        const float bb = bias[n];
#pragma unroll
        for (int r = 0; r < 4; ++r)
          outf[(size_t)(m0 + r) * N + n] = v[r] + bb + res[(size_t)(m0 + r) * N + n];
      } else { // EPI 5: fused QKV
        const int seg = blockIdx.y >> 2;          // 0=Q 1=K 2=V (uniform per block)
        if (seg == 0) {
          // fold softmax scale (1/sqrt(64) * log2(e)) into Q, exact in fp32
#pragma unroll
          for (int r = 0; r < 4; ++r)
            outb[(size_t)(m0 + r) * 512 + n] = (bf16_t)(v[r] * 0.180336879f);
        } else if (seg == 1) {
#pragma unroll
          for (int r = 0; r < 4; ++r) out2[(size_t)(m0 + r) * 512 + (n - 512)] = (bf16_t)v[r];
        } else {
          // sigma-permute keys within 32-groups so attn PV A-frags are contiguous:
          // stored p = (o&3) + ((o>>2)&3)*8 + ((o>>4)&1)*4, o = m0&31 (mult of 4)
          const int o = m0 & 31;
          const int p0 = (m0 & ~31) + ((o >> 2) & 3) * 8 + ((o >> 4) << 2);
          bf16x4 pk = {(bf16_t)v[0], (bf16_t)v[1], (bf16_t)v[2], (bf16_t)v[3]};
          *(bf16x4*)(out3 + (size_t)(n - 1024) * ldt + p0) = pk;
        }
      }
    }
  }
}

// ---------------- Flash attention: K in registers, V-only LDS ---------------
// grid (S/64, H, B) = 1024 blocks; 4 waves x 16 q-rows. LDS = 16 KB (V only).
// QK A-frags loaded straight from global (64 VGPRs, L2-served, coalesced 64B).
// S^T C-layout (rows=keys quad*4+r, cols=qrow l16) feeds K=32 PV via kappa
// permutation; V^T stored sigma-permuted so each PV A-frag is one b128 read.
__global__ __launch_bounds__(256, 4)
void attn_kernel(const bf16_t* __restrict__ qm, const bf16_t* __restrict__ km,
                 const bf16_t* __restrict__ vtm, const int* __restrict__ mask,
                 bf16_t* __restrict__ ctx)
{
  const int b = blockIdx.z, h = blockIdx.y;
  const int q0 = blockIdx.x * 64;
  const int tid = threadIdx.x;
  const int wave = tid >> 6, lane = tid & 63;
  const int quad = lane >> 4, l16 = lane & 15;

  __shared__ __align__(16) bf16_t lV[DHD * 128];      // [dh][stored key]  16 KB
  __shared__ int sclean[4];

  const int* maskb = mask + b * SS;

  // ---- block-level mask pre-check: umin over all 4096 ints ----
  unsigned um = 0xFFFFFFFFu;
#pragma unroll
  for (int i = 0; i < 4; ++i) {
    int4 m = *(const int4*)(maskb + tid * 16 + i * 4);
    um = min(um, min(min((unsigned)m.x, (unsigned)m.y), min((unsigned)m.z, (unsigned)m.w)));
  }
#pragma unroll
  for (int o = 1; o < 64; o <<= 1) um = min(um, (unsigned)__shfl_xor((int)um, o));
  if (lane == 0) sclean[wave] = (int)um;
  __syncthreads();
  const bool clean = (min(min((unsigned)sclean[0], (unsigned)sclean[1]),
                          min((unsigned)sclean[2], (unsigned)sclean[3])) != 0u);

  const size_t qrow0 = (size_t)b * SS + q0;
  // Q as B-operand frags (n=qrow=l16, k=dh=quad*8+t), pre-scaled by softmax factor
  bf16x8 qa[2];
#pragma unroll
  for (int c = 0; c < 2; ++c)
    qa[c] = *(const bf16x8*)(qm + (qrow0 + wave * 16 + l16) * DM
                             + h * DHD + c * 32 + quad * 8);

  bf16x8 vone8;
#pragma unroll
  for (int t = 0; t < 8; ++t) vone8[t] = (bf16_t)1.0f;

  const floatx4 vzero = {0.f, 0.f, 0.f, 0.f};
  floatx4 cacc[4], lacc;
  lacc = vzero;
#pragma unroll
  for (int nb = 0; nb < 4; ++nb) cacc[nb] = vzero;

  // per-lane K fragment base: row l16, dh col quad*8 within head
  const bf16_t* Kf = km + ((size_t)b * SS + l16) * DM + h * DHD + quad * 8;
  const bf16_t* Vb = vtm + (size_t)(h * DHD) * MT + (size_t)b * SS;

  for (int s0 = 0; s0 < SS; s0 += 128) {
    __syncthreads();
    // ---- K fragments straight from global (no LDS): 16 x 16B per lane ----
    bf16x8 kf[4][2][2];
#pragma unroll
    for (int c = 0; c < 4; ++c)
#pragma unroll
      for (int hf = 0; hf < 2; ++hf)
#pragma unroll
        for (int cc = 0; cc < 2; ++cc)
          kf[c][hf][cc] = *(const bf16x8*)(Kf + (size_t)(s0 + c * 32 + hf * 16) * DM + cc * 32);
    // ---- stage V tile (16 KB, 4 instrs/thread) ----
#pragma unroll
    for (int i = 0; i < 4; ++i) {
      int p = tid + 256 * i;
      int dh = p >> 4;
      int cs = (p & 15) ^ (dh & 7);
      async_copy16(Vb + (size_t)dh * MT + s0 + cs * 8, lV + p * 8);
    }
    __syncthreads();

    // ---- per 32-key chunk: S^T (2 blocks) -> exp2 -> K=32 PV ----
#pragma unroll
    for (int c = 0; c < 4; ++c) {
      floatx4 sa = vzero, sb = vzero;
#pragma unroll
      for (int cc = 0; cc < 2; ++cc) {
        sa = __builtin_amdgcn_mfma_f32_16x16x32_bf16(kf[c][0][cc], qa[cc], sa, 0, 0, 0);
        sb = __builtin_amdgcn_mfma_f32_16x16x32_bf16(kf[c][1][cc], qa[cc], sb, 0, 0, 0);
      }

      if (!clean) {   // rare path: -inf where mask==0 (keys quad*4+r within block)
        const int4 m0 = *(const int4*)(maskb + s0 + c * 32 + quad * 4);
        const int4 m1 = *(const int4*)(maskb + s0 + c * 32 + 16 + quad * 4);
        if (m0.x == 0) sa[0] = -1e30f;
        if (m0.y == 0) sa[1] = -1e30f;
        if (m0.z == 0) sa[2] = -1e30f;
        if (m0.w == 0) sa[3] = -1e30f;
        if (m1.x == 0) sb[0] = -1e30f;
        if (m1.y == 0) sb[1] = -1e30f;
        if (m1.z == 0) sb[2] = -1e30f;
        if (m1.w == 0) sb[3] = -1e30f;
      }

      bf16x8 pf;
      pf[0] = (bf16_t)fast_exp2(sa[0]); pf[1] = (bf16_t)fast_exp2(sa[1]);
      pf[2] = (bf16_t)fast_exp2(sa[2]); pf[3] = (bf16_t)fast_exp2(sa[3]);
      pf[4] = (bf16_t)fast_exp2(sb[0]); pf[5] = (bf16_t)fast_exp2(sb[1]);
      pf[6] = (bf16_t)fast_exp2(sb[2]); pf[7] = (bf16_t)fast_exp2(sb[3]);

      lacc = __builtin_amdgcn_mfma_f32_16x16x32_bf16(vone8, pf, lacc, 0, 0, 0);
      const int ch = (c * 4 + quad) ^ (l16 & 7);
#pragma unroll
      for (int nb = 0; nb < 4; ++nb) {
        bf16x8 av = *(const bf16x8*)(lV + (nb * 16 + l16) * 128 + ch * 8);
        cacc[nb] = __builtin_amdgcn_mfma_f32_16x16x32_bf16(av, pf, cacc[nb], 0, 0, 0);
      }
    }
  }

  // ---- epilogue: O^T cols=qrow=l16, rows=dh=nb*16+quad*4+r -> 8B stores ----
  const float inv = 1.0f / lacc[0];
  const size_t qrow = qrow0 + wave * 16 + l16;
#pragma unroll
  for (int nb = 0; nb < 4; ++nb) {
    bf16x4 o = {(bf16_t)(cacc[nb][0] * inv), (bf16_t)(cacc[nb][1] * inv),
                (bf16_t)(cacc[nb][2] * inv), (bf16_t)(cacc[nb][3] * inv)};
    *(bf16x4*)(ctx + qrow * DM + h * DHD + nb * 16 + quad * 4) = o;
  }
}

// ---------------------------------------------------------------------------
extern "C" void kernel_launch(void* const* d_in, const int* in_sizes, int n_in,
                              void* d_out, int out_size, void* d_ws, size_t ws_size,
                              hipStream_t stream)
{
  (void)in_sizes; (void)n_in; (void)out_size; (void)ws_size;
  const float* reaction = (const float*)d_in[0];
  const int*   mask     = (const int*)d_in[1];
  const float* Wq = (const float*)d_in[2];
  const float* Wk = (const float*)d_in[3];
  const float* Wv = (const float*)d_in[4];
  const float* Wo = (const float*)d_in[5];
  const float* bo = (const float*)d_in[6];
  const float* W1 = (const float*)d_in[7];
  const float* b1 = (const float*)d_in[8];
  const float* W2 = (const float*)d_in[9];
  const float* b2 = (const float*)d_in[10];
  const float* g_sa = (const float*)d_in[11];
  const float* b_sa = (const float*)d_in[12];
  const float* g_ff = (const float*)d_in[13];
  const float* b_ff = (const float*)d_in[14];
  float* out = (float*)d_out;

  char* ws = (char*)d_ws;
  size_t off = 0;
  auto take = [&](size_t bytes) -> char* {
    char* p = ws + off;
    off += (bytes + 255) & ~(size_t)255;
    return p;
  };

  bf16_t* xln   = (bf16_t*)take((size_t)MT * DM * 2);       // LN1 out; reused as LN2 out
  bf16_t* WqkvT = (bf16_t*)take((size_t)3 * DM * DM * 2);   // [1536][512]
  bf16_t* WoT   = (bf16_t*)take((size_t)DM * DM * 2);
  bf16_t* W1T   = (bf16_t*)take((size_t)FFD * DM * 2);
  bf16_t* W2T   = (bf16_t*)take((size_t)DM * FFD * 2);
  bf16_t* qb    = (bf16_t*)take((size_t)MT * DM * 2);       // qb..ctx contiguous 32MB,
  bf16_t* kb    = (bf16_t*)take((size_t)MT * DM * 2);       // reused as FFN hidden h
  bf16_t* vtb   = (bf16_t*)take((size_t)DM * MT * 2);       // V transposed [D, M], sigma-permuted
  bf16_t* ctx   = (bf16_t*)take((size_t)MT * DM * 2);
  float*  x2    = (float*)take((size_t)MT * DM * 4);
  bf16_t* yb    = xln;
  bf16_t* hb    = qb;   // 8192*2048 bf16 = 32MB over qb/kb/vtb/ctx (all dead by then)

  ln_kernel<<<MT, 256, 0, stream>>>(reaction, g_sa, b_sa, xln);
  prep_weights<<<3072, 256, 0, stream>>>(Wq, Wk, Wv, Wo, W1, W2, WqkvT, WoT, W1T, W2T);

  // Fused QKV projection (Q pre-scaled, V stored transposed + sigma-permuted)
  gemm_bt<4, 4, 5><<<dim3(64, 12), 256, 0, stream>>>(xln, WqkvT, MT, 3 * DM, DM,
                                                     nullptr, nullptr, qb, nullptr, kb, vtb, MT);

  attn_kernel<<<dim3(SS / 64, HN, BB), 256, 0, stream>>>(qb, kb, vtb, mask, ctx);

  // Output projection + GELU + residual -> x2 (fp32); 64x64 tiles, 4 blocks/CU
  gemm_bt<2, 2, 2><<<dim3(128, 8), 256, 0, stream>>>(ctx, WoT, MT, DM, DM,
                                                     bo, reaction, nullptr, x2, nullptr, nullptr, 0);

  ln_kernel<<<MT, 256, 0, stream>>>(x2, g_ff, b_ff, yb);
  gemm_bt<4, 4, 3><<<dim3(64, 16), 256, 0, stream>>>(yb, W1T, MT, FFD, DM,
                                                     b1, nullptr, hb, nullptr, nullptr, nullptr, 0);
  gemm_bt<2, 2, 4><<<dim3(128, 8), 256, 0, stream>>>(hb, W2T, MT, DM, FFD,
                                                     b2, x2, nullptr, out, nullptr, nullptr, 0);
}

// Round 9
// 283.294 us; speedup vs baseline: 1.6315x; 1.6315x over previous
//
#include <hip/hip_runtime.h>
#include <hip/hip_bf16.h>
#include <math.h>

#define HN 8
#define DM 512
#define DHD 64
#define FFD 2048
#define BB 2
#define SS 4096
#define MT (BB*SS)   // 8192 token rows

typedef __bf16 bf16_t;
typedef __bf16 bf16x8 __attribute__((ext_vector_type(8)));
typedef __bf16 bf16x4 __attribute__((ext_vector_type(4)));
typedef float  floatx4 __attribute__((ext_vector_type(4)));

// Async global->LDS. NOTE (m104/m108): LDS dest is wave-uniform base + lane*16;
// all swizzling must be applied on the GLOBAL SOURCE side, LDS dest stays linear.
__device__ __forceinline__ void async_copy16(const bf16_t* g, bf16_t* l) {
  __builtin_amdgcn_global_load_lds((const __attribute__((address_space(1))) void*)g,
                                   (__attribute__((address_space(3))) void*)l,
                                   16, 0, 0);
}

__device__ __forceinline__ float gelu_f(float x) {
  return 0.5f * x * (1.0f + erff(x * 0.70710678118654752f));
}

#if __has_builtin(__builtin_amdgcn_exp2f)
__device__ __forceinline__ float fast_exp2(float x) { return __builtin_amdgcn_exp2f(x); }
#else
__device__ __forceinline__ float fast_exp2(float x) { return __expf(x * 0.69314718056f); }
#endif

// ---------------- LayerNorm: fp32 in -> bf16 out, fused gamma/beta ----------
__global__ __launch_bounds__(256)
void ln_kernel(const float* __restrict__ x, const float* __restrict__ g,
               const float* __restrict__ be, bf16_t* __restrict__ out)
{
  const int row = blockIdx.x, t = threadIdx.x;
  const float* xr = x + (size_t)row * DM;
  float v0 = xr[t], v1 = xr[t + 256];
  float s = v0 + v1, s2 = v0 * v0 + v1 * v1;
#pragma unroll
  for (int o = 32; o > 0; o >>= 1) { s += __shfl_down(s, o); s2 += __shfl_down(s2, o); }
  __shared__ float red[8];
  if ((t & 63) == 0) { red[(t >> 6) * 2] = s; red[(t >> 6) * 2 + 1] = s2; }
  __syncthreads();
  float ts  = red[0] + red[2] + red[4] + red[6];
  float ts2 = red[1] + red[3] + red[5] + red[7];
  float mu = ts * (1.0f / DM);
  float rv = rsqrtf(ts2 * (1.0f / DM) - mu * mu + 1e-5f);
  out[(size_t)row * DM + t]       = (bf16_t)((v0 - mu) * rv * g[t]       + be[t]);
  out[(size_t)row * DM + t + 256] = (bf16_t)((v1 - mu) * rv * g[t + 256] + be[t + 256]);
}

// ------------- Fused weight prep: all 6 transposes in one launch ------------
__global__ __launch_bounds__(256)
void prep_weights(const float* __restrict__ Wq, const float* __restrict__ Wk,
                  const float* __restrict__ Wv, const float* __restrict__ Wo,
                  const float* __restrict__ W1, const float* __restrict__ W2,
                  bf16_t* __restrict__ WqkvT, bf16_t* __restrict__ WoT,
                  bf16_t* __restrict__ W1T, bf16_t* __restrict__ W2T)
{
  const int bid = blockIdx.x;
  const float* src; bf16_t* dst; int Kd, Nd, n0, k0;
  if (bid < 768) {
    int seg = bid >> 8, t = bid & 255;
    src = (seg == 0) ? Wq : (seg == 1) ? Wk : Wv;
    dst = WqkvT + (size_t)seg * 512 * 512;
    Kd = 512; Nd = 512; n0 = (t & 15) * 32; k0 = (t >> 4) * 32;
  } else if (bid < 1024) {
    int t = bid - 768; src = Wo; dst = WoT;
    Kd = 512; Nd = 512; n0 = (t & 15) * 32; k0 = (t >> 4) * 32;
  } else if (bid < 2048) {
    int t = bid - 1024; src = W1; dst = W1T;
    Kd = 512; Nd = 2048; n0 = (t & 63) * 32; k0 = (t >> 6) * 32;
  } else {
    int t = bid - 2048; src = W2; dst = W2T;
    Kd = 2048; Nd = 512; n0 = (t & 15) * 32; k0 = (t >> 4) * 32;
  }
  __shared__ float tile[32][33];
  const int tx = threadIdx.x & 31, ty = threadIdx.x >> 5;
#pragma unroll
  for (int i = 0; i < 32; i += 8)
    tile[ty + i][tx] = src[(size_t)(k0 + ty + i) * Nd + n0 + tx];
  __syncthreads();
#pragma unroll
  for (int i = 0; i < 32; i += 8)
    dst[(size_t)(n0 + ty + i) * Kd + k0 + tx] = (bf16_t)tile[tx][ty + i];
}

// ---------------- GEMM: C[M,N] = A[M,K] * Bt[N,K]^T, bf16 MFMA --------------
// Tile = (32*MI) x (32*NJ), BK=64, 4 waves in 2x2; wave computes MI x NJ
// 16x16 output blocks. Staging: linear LDS dest, source chunk XOR row&7.
// EPI: 2 = f32 gelu(acc+bias)+res; 3 = bf16 gelu(acc+bias); 4 = f32 acc+bias+res
//      5 = fused-QKV epilogue (q scaled, k row-major, v transposed+sigma-permuted)
template <int MI, int NJ, int EPI>
__global__ __launch_bounds__(256)
void gemm_bt(const bf16_t* __restrict__ A, const bf16_t* __restrict__ Bt,
             const int M, const int N, const int K,
             const float* __restrict__ bias, const float* __restrict__ res,
             bf16_t* __restrict__ outb, float* __restrict__ outf,
             bf16_t* __restrict__ out2, bf16_t* __restrict__ out3, const int ldt)
{
  constexpr int MTILE = 32 * MI, NTILE = 32 * NJ;
  constexpr int ACOPY = MTILE / 32;    // staging instrs per thread (BK=64)
  constexpr int BCOPY = NTILE / 32;
  __shared__ __align__(16) bf16_t lA[MTILE * 64];
  __shared__ __align__(16) bf16_t lB[NTILE * 64];
  const int tid = threadIdx.x;
  const int wave = tid >> 6, lane = tid & 63;
  const int wm = wave & 1, wn = wave >> 1;
  const int quad = lane >> 4, l16 = lane & 15;

  int srA[ACOPY > BCOPY ? ACOPY : BCOPY], scA[ACOPY > BCOPY ? ACOPY : BCOPY];
#pragma unroll
  for (int i = 0; i < (ACOPY > BCOPY ? ACOPY : BCOPY); ++i) {
    int flat = tid + 256 * i;
    int r = flat >> 3, ch = flat & 7;
    srA[i] = r;
    scA[i] = (ch ^ (r & 7)) * 8;       // source-side swizzle, dest stays linear
  }
  const bf16_t* Ab = A + (size_t)(blockIdx.x * MTILE) * K;
  const bf16_t* Bb = Bt + (size_t)(blockIdx.y * NTILE) * K;

  const floatx4 vzero = {0.f, 0.f, 0.f, 0.f};
  floatx4 acc[MI][NJ];
#pragma unroll
  for (int i = 0; i < MI; ++i)
#pragma unroll
    for (int j = 0; j < NJ; ++j) acc[i][j] = vzero;

  for (int k0 = 0; k0 < K; k0 += 64) {
    __syncthreads();
#pragma unroll
    for (int i = 0; i < ACOPY; ++i)
      async_copy16(Ab + (size_t)srA[i] * K + k0 + scA[i], lA + (tid + 256 * i) * 8);
#pragma unroll
    for (int i = 0; i < BCOPY; ++i)
      async_copy16(Bb + (size_t)srA[i] * K + k0 + scA[i], lB + (tid + 256 * i) * 8);
    __syncthreads();
#pragma unroll
    for (int c = 0; c < 2; ++c) {
      bf16x8 af[MI], bfv[NJ];
#pragma unroll
      for (int i = 0; i < MI; ++i)
        af[i] = *(const bf16x8*)(lA + (wm * 16 * MI + i * 16 + l16) * 64
                                 + (((c * 4 + quad) ^ (l16 & 7)) * 8));
#pragma unroll
      for (int j = 0; j < NJ; ++j)
        bfv[j] = *(const bf16x8*)(lB + (wn * 16 * NJ + j * 16 + l16) * 64
                                  + (((c * 4 + quad) ^ (l16 & 7)) * 8));
#pragma unroll
      for (int i = 0; i < MI; ++i)
#pragma unroll
        for (int j = 0; j < NJ; ++j)
          acc[i][j] = __builtin_amdgcn_mfma_f32_16x16x32_bf16(af[i], bfv[j], acc[i][j], 0, 0, 0);
    }
  }

  const int m00 = blockIdx.x * MTILE + wm * 16 * MI;
  const int n00 = blockIdx.y * NTILE + wn * 16 * NJ;
#pragma unroll
  for (int i = 0; i < MI; ++i) {
#pragma unroll
    for (int j = 0; j < NJ; ++j) {
      const int m0 = m00 + i * 16 + quad * 4;     // C/D: row=quad*4+reg, col=l16
      const int n  = n00 + j * 16 + l16;
      floatx4 v = acc[i][j];
      if (EPI == 2) {
        const float bb = bias[n];
#pragma unroll
        for (int r = 0; r < 4; ++r)
          outf[(size_t)(m0 + r) * N + n] = gelu_f(v[r] + bb) + res[(size_t)(m0 + r) * N + n];
      } else if (EPI == 3) {
        const float bb = bias[n];
#pragma unroll
        for (int r = 0; r < 4; ++r)
          outb[(size_t)(m0 + r) * N + n] = (bf16_t)gelu_f(v[r] + bb);
      } else if (EPI == 4) {
        const float bb = bias[n];
#pragma unroll
        for (int r = 0; r < 4; ++r)
          outf[(size_t)(m0 + r) * N + n] = v[r] + bb + res[(size_t)(m0 + r) * N + n];
      } else { // EPI 5: fused QKV
        const int seg = blockIdx.y >> 2;          // 0=Q 1=K 2=V (uniform per block)
        if (seg == 0) {
          // fold softmax scale (1/sqrt(64) * log2(e)) into Q, exact in fp32
#pragma unroll
          for (int r = 0; r < 4; ++r)
            outb[(size_t)(m0 + r) * 512 + n] = (bf16_t)(v[r] * 0.180336879f);
        } else if (seg == 1) {
#pragma unroll
          for (int r = 0; r < 4; ++r) out2[(size_t)(m0 + r) * 512 + (n - 512)] = (bf16_t)v[r];
        } else {
          // sigma-permute keys within 32-groups so attn PV A-frags are contiguous:
          // stored p = (o&3) + ((o>>2)&3)*8 + ((o>>4)&1)*4, o = m0&31 (mult of 4)
          const int o = m0 & 31;
          const int p0 = (m0 & ~31) + ((o >> 2) & 3) * 8 + ((o >> 4) << 2);
          bf16x4 pk = {(bf16_t)v[0], (bf16_t)v[1], (bf16_t)v[2], (bf16_t)v[3]};
          *(bf16x4*)(out3 + (size_t)(n - 1024) * ldt + p0) = pk;
        }
      }
    }
  }
}

// ---------------- Flash attention: Q-tile 128, 4 waves x 32 q-rows ----------
// grid (S/128, H, B) = 512 blocks (2/CU, 8 waves/CU); LDS 32 KB (K 16 + V 16).
// S^T = mfma(K-frag, Q-frag): C-layout rows=keys (quad*4+r), cols=qrow (l16).
// kappa-permuted K=32 PV: B-operand = concat of two exp2'd S^T C-regs;
// sigma-permuted V^T makes each PV A-frag one contiguous b128 read, shared
// across both 16-q-row groups -> LDS read traffic halves vs 16-row waves.
__global__ __launch_bounds__(256, 2)
void attn_kernel(const bf16_t* __restrict__ qm, const bf16_t* __restrict__ km,
                 const bf16_t* __restrict__ vtm, const int* __restrict__ mask,
                 bf16_t* __restrict__ ctx)
{
  const int b = blockIdx.z, h = blockIdx.y;
  const int q0 = blockIdx.x * 128;
  const int tid = threadIdx.x;
  const int wave = tid >> 6, lane = tid & 63;
  const int quad = lane >> 4, l16 = lane & 15;

  __shared__ __align__(16) bf16_t lK[128 * DHD];      // [key][dh]          16 KB
  __shared__ __align__(16) bf16_t lV[DHD * 128];      // [dh][stored key]   16 KB
  __shared__ int sclean[4];

  const int* maskb = mask + b * SS;

  // ---- block-level mask pre-check: umin over all 4096 ints ----
  unsigned um = 0xFFFFFFFFu;
#pragma unroll
  for (int i = 0; i < 4; ++i) {
    int4 m = *(const int4*)(maskb + tid * 16 + i * 4);
    um = min(um, min(min((unsigned)m.x, (unsigned)m.y), min((unsigned)m.z, (unsigned)m.w)));
  }
#pragma unroll
  for (int o = 1; o < 64; o <<= 1) um = min(um, (unsigned)__shfl_xor((int)um, o));
  if (lane == 0) sclean[wave] = (int)um;
  __syncthreads();
  const bool clean = (min(min((unsigned)sclean[0], (unsigned)sclean[1]),
                          min((unsigned)sclean[2], (unsigned)sclean[3])) != 0u);

  const size_t qrow0 = (size_t)b * SS + q0;
  // Q as B-operand frags (n=qrow=l16, k=dh=quad*8+t), pre-scaled by softmax factor
  bf16x8 qa[2][2];
#pragma unroll
  for (int mb = 0; mb < 2; ++mb)
#pragma unroll
    for (int cc = 0; cc < 2; ++cc)
      qa[mb][cc] = *(const bf16x8*)(qm + (qrow0 + wave * 32 + mb * 16 + l16) * DM
                                    + h * DHD + cc * 32 + quad * 8);

  bf16x8 vone8;
#pragma unroll
  for (int t = 0; t < 8; ++t) vone8[t] = (bf16_t)1.0f;

  const floatx4 vzero = {0.f, 0.f, 0.f, 0.f};
  floatx4 cacc[2][4], lacc[2];
#pragma unroll
  for (int mb = 0; mb < 2; ++mb) {
    lacc[mb] = vzero;
#pragma unroll
    for (int nb = 0; nb < 4; ++nb) cacc[mb][nb] = vzero;
  }

  const bf16_t* Kb = km + (size_t)b * SS * DM + h * DHD;
  const bf16_t* Vb = vtm + (size_t)(h * DHD) * MT + (size_t)b * SS;

  for (int s0 = 0; s0 < SS; s0 += 128) {
    __syncthreads();
#pragma unroll
    for (int i = 0; i < 4; ++i) {
      int p = tid + 256 * i;
      int key = p >> 3;
      int cs = (p & 7) ^ (key & 7);
      async_copy16(Kb + (size_t)(s0 + key) * DM + cs * 8, lK + p * 8);
      int dh = p >> 4;
      int cs2 = (p & 15) ^ (dh & 7);
      async_copy16(Vb + (size_t)dh * MT + s0 + cs2 * 8, lV + p * 8);
    }
    __syncthreads();

    // ---- per 32-key chunk: S^T (2 key-blocks x 2 q-groups) -> exp2 -> PV ----
#pragma unroll
    for (int c = 0; c < 4; ++c) {
      floatx4 sa[2], sb[2];
      sa[0] = vzero; sa[1] = vzero; sb[0] = vzero; sb[1] = vzero;
#pragma unroll
      for (int cc = 0; cc < 2; ++cc) {
        const int ko = ((cc * 4 + quad) ^ (l16 & 7)) * 8;
        bf16x8 kf0 = *(const bf16x8*)(lK + (c * 32 + l16) * 64 + ko);
        bf16x8 kf1 = *(const bf16x8*)(lK + (c * 32 + 16 + l16) * 64 + ko);
#pragma unroll
        for (int mb = 0; mb < 2; ++mb) {
          sa[mb] = __builtin_amdgcn_mfma_f32_16x16x32_bf16(kf0, qa[mb][cc], sa[mb], 0, 0, 0);
          sb[mb] = __builtin_amdgcn_mfma_f32_16x16x32_bf16(kf1, qa[mb][cc], sb[mb], 0, 0, 0);
        }
      }

      if (!clean) {   // rare path: -inf where mask==0 (keys quad*4+r within block)
        const int4 m0 = *(const int4*)(maskb + s0 + c * 32 + quad * 4);
        const int4 m1 = *(const int4*)(maskb + s0 + c * 32 + 16 + quad * 4);
#pragma unroll
        for (int mb = 0; mb < 2; ++mb) {
          if (m0.x == 0) sa[mb][0] = -1e30f;
          if (m0.y == 0) sa[mb][1] = -1e30f;
          if (m0.z == 0) sa[mb][2] = -1e30f;
          if (m0.w == 0) sa[mb][3] = -1e30f;
          if (m1.x == 0) sb[mb][0] = -1e30f;
          if (m1.y == 0) sb[mb][1] = -1e30f;
          if (m1.z == 0) sb[mb][2] = -1e30f;
          if (m1.w == 0) sb[mb][3] = -1e30f;
        }
      }

      bf16x8 pf[2];
#pragma unroll
      for (int mb = 0; mb < 2; ++mb) {
        pf[mb][0] = (bf16_t)fast_exp2(sa[mb][0]); pf[mb][1] = (bf16_t)fast_exp2(sa[mb][1]);
        pf[mb][2] = (bf16_t)fast_exp2(sa[mb][2]); pf[mb][3] = (bf16_t)fast_exp2(sa[mb][3]);
        pf[mb][4] = (bf16_t)fast_exp2(sb[mb][0]); pf[mb][5] = (bf16_t)fast_exp2(sb[mb][1]);
        pf[mb][6] = (bf16_t)fast_exp2(sb[mb][2]); pf[mb][7] = (bf16_t)fast_exp2(sb[mb][3]);
        lacc[mb] = __builtin_amdgcn_mfma_f32_16x16x32_bf16(vone8, pf[mb], lacc[mb], 0, 0, 0);
      }
      const int ch = (c * 4 + quad) ^ (l16 & 7);
#pragma unroll
      for (int nb = 0; nb < 4; ++nb) {
        bf16x8 av = *(const bf16x8*)(lV + (nb * 16 + l16) * 128 + ch * 8);
        cacc[0][nb] = __builtin_amdgcn_mfma_f32_16x16x32_bf16(av, pf[0], cacc[0][nb], 0, 0, 0);
        cacc[1][nb] = __builtin_amdgcn_mfma_f32_16x16x32_bf16(av, pf[1], cacc[1][nb], 0, 0, 0);
      }
    }
  }

  // ---- epilogue: O^T cols=qrow=l16, rows=dh=nb*16+quad*4+r -> 8B stores ----
#pragma unroll
  for (int mb = 0; mb < 2; ++mb) {
    const float inv = 1.0f / lacc[mb][0];
    const size_t qrow = qrow0 + wave * 32 + mb * 16 + l16;
#pragma unroll
    for (int nb = 0; nb < 4; ++nb) {
      bf16x4 o = {(bf16_t)(cacc[mb][nb][0] * inv), (bf16_t)(cacc[mb][nb][1] * inv),
                  (bf16_t)(cacc[mb][nb][2] * inv), (bf16_t)(cacc[mb][nb][3] * inv)};
      *(bf16x4*)(ctx + qrow * DM + h * DHD + nb * 16 + quad * 4) = o;
    }
  }
}

// ---------------------------------------------------------------------------
extern "C" void kernel_launch(void* const* d_in, const int* in_sizes, int n_in,
                              void* d_out, int out_size, void* d_ws, size_t ws_size,
                              hipStream_t stream)
{
  (void)in_sizes; (void)n_in; (void)out_size; (void)ws_size;
  const float* reaction = (const float*)d_in[0];
  const int*   mask     = (const int*)d_in[1];
  const float* Wq = (const float*)d_in[2];
  const float* Wk = (const float*)d_in[3];
  const float* Wv = (const float*)d_in[4];
  const float* Wo = (const float*)d_in[5];
  const float* bo = (const float*)d_in[6];
  const float* W1 = (const float*)d_in[7];
  const float* b1 = (const float*)d_in[8];
  const float* W2 = (const float*)d_in[9];
  const float* b2 = (const float*)d_in[10];
  const float* g_sa = (const float*)d_in[11];
  const float* b_sa = (const float*)d_in[12];
  const float* g_ff = (const float*)d_in[13];
  const float* b_ff = (const float*)d_in[14];
  float* out = (float*)d_out;

  char* ws = (char*)d_ws;
  size_t off = 0;
  auto take = [&](size_t bytes) -> char* {
    char* p = ws + off;
    off += (bytes + 255) & ~(size_t)255;
    return p;
  };

  bf16_t* xln   = (bf16_t*)take((size_t)MT * DM * 2);       // LN1 out; reused as LN2 out
  bf16_t* WqkvT = (bf16_t*)take((size_t)3 * DM * DM * 2);   // [1536][512]
  bf16_t* WoT   = (bf16_t*)take((size_t)DM * DM * 2);
  bf16_t* W1T   = (bf16_t*)take((size_t)FFD * DM * 2);
  bf16_t* W2T   = (bf16_t*)take((size_t)DM * FFD * 2);
  bf16_t* qb    = (bf16_t*)take((size_t)MT * DM * 2);       // qb..ctx contiguous 32MB,
  bf16_t* kb    = (bf16_t*)take((size_t)MT * DM * 2);       // reused as FFN hidden h
  bf16_t* vtb   = (bf16_t*)take((size_t)DM * MT * 2);       // V transposed [D, M], sigma-permuted
  bf16_t* ctx   = (bf16_t*)take((size_t)MT * DM * 2);
  float*  x2    = (float*)take((size_t)MT * DM * 4);
  bf16_t* yb    = xln;
  bf16_t* hb    = qb;   // 8192*2048 bf16 = 32MB over qb/kb/vtb/ctx (all dead by then)

  ln_kernel<<<MT, 256, 0, stream>>>(reaction, g_sa, b_sa, xln);
  prep_weights<<<3072, 256, 0, stream>>>(Wq, Wk, Wv, Wo, W1, W2, WqkvT, WoT, W1T, W2T);

  // Fused QKV projection (Q pre-scaled, V stored transposed + sigma-permuted)
  gemm_bt<4, 4, 5><<<dim3(64, 12), 256, 0, stream>>>(xln, WqkvT, MT, 3 * DM, DM,
                                                     nullptr, nullptr, qb, nullptr, kb, vtb, MT);

  attn_kernel<<<dim3(SS / 128, HN, BB), 256, 0, stream>>>(qb, kb, vtb, mask, ctx);

  // Output projection + GELU + residual -> x2 (fp32); 64x64 tiles, 4 blocks/CU
  gemm_bt<2, 2, 2><<<dim3(128, 8), 256, 0, stream>>>(ctx, WoT, MT, DM, DM,
                                                     bo, reaction, nullptr, x2, nullptr, nullptr, 0);

  ln_kernel<<<MT, 256, 0, stream>>>(x2, g_ff, b_ff, yb);
  gemm_bt<4, 4, 3><<<dim3(64, 16), 256, 0, stream>>>(yb, W1T, MT, FFD, DM,
                                                     b1, nullptr, hb, nullptr, nullptr, nullptr, 0);
  gemm_bt<2, 2, 4><<<dim3(128, 8), 256, 0, stream>>>(hb, W2T, MT, DM, FFD,
                                                     b2, x2, nullptr, out, nullptr, nullptr, 0);
}

// Round 10
// 276.523 us; speedup vs baseline: 1.6715x; 1.0245x over previous
//
#include <hip/hip_runtime.h>
#include <hip/hip_bf16.h>
#include <math.h>

#define HN 8
#define DM 512
#define DHD 64
#define FFD 2048
#define BB 2
#define SS 4096
#define MT (BB*SS)   // 8192 token rows

typedef __bf16 bf16_t;
typedef __bf16 bf16x8 __attribute__((ext_vector_type(8)));
typedef __bf16 bf16x4 __attribute__((ext_vector_type(4)));
typedef float  floatx4 __attribute__((ext_vector_type(4)));

// Async global->LDS. NOTE (m104/m108): LDS dest is wave-uniform base + lane*16;
// all swizzling must be applied on the GLOBAL SOURCE side, LDS dest stays linear.
__device__ __forceinline__ void async_copy16(const bf16_t* g, bf16_t* l) {
  __builtin_amdgcn_global_load_lds((const __attribute__((address_space(1))) void*)g,
                                   (__attribute__((address_space(3))) void*)l,
                                   16, 0, 0);
}

#if __has_builtin(__builtin_amdgcn_exp2f)
__device__ __forceinline__ float fast_exp2(float x) { return __builtin_amdgcn_exp2f(x); }
#else
__device__ __forceinline__ float fast_exp2(float x) { return __expf(x * 0.69314718056f); }
#endif

// tanh-form GELU via exp2 (max |err| vs exact erf-GELU ~3e-3, ~10 VALU ops)
__device__ __forceinline__ float gelu_f(float x) {
  float y = 0.7978845608f * (x + 0.044715f * x * x * x);
  float e = fast_exp2(y * 2.885390082f);   // exp(2y)
  float th = 1.0f - 2.0f / (e + 1.0f);
  return 0.5f * x * (1.0f + th);
}

// ------- LayerNorm: fp32 in -> bf16 out; 1 wave per row, 4 rows/block -------
__global__ __launch_bounds__(256)
void ln_kernel(const float* __restrict__ x, const float* __restrict__ g,
               const float* __restrict__ be, bf16_t* __restrict__ out)
{
  const int wave = threadIdx.x >> 6, lane = threadIdx.x & 63;
  const int row = blockIdx.x * 4 + wave;
  const float* xr = x + (size_t)row * DM + lane * 8;
  float4 a = *(const float4*)xr;
  float4 c = *(const float4*)(xr + 4);
  float s  = (a.x + a.y) + (a.z + a.w) + (c.x + c.y) + (c.z + c.w);
  float s2 = (a.x*a.x + a.y*a.y) + (a.z*a.z + a.w*a.w)
           + (c.x*c.x + c.y*c.y) + (c.z*c.z + c.w*c.w);
#pragma unroll
  for (int o = 1; o < 64; o <<= 1) { s += __shfl_xor(s, o); s2 += __shfl_xor(s2, o); }
  const float mu = s * (1.0f / DM);
  const float rv = rsqrtf(s2 * (1.0f / DM) - mu * mu + 1e-5f);
  float4 g0 = *(const float4*)(g + lane * 8);
  float4 g1 = *(const float4*)(g + lane * 8 + 4);
  float4 b0 = *(const float4*)(be + lane * 8);
  float4 b1 = *(const float4*)(be + lane * 8 + 4);
  bf16x8 o8;
  o8[0] = (bf16_t)((a.x - mu) * rv * g0.x + b0.x);
  o8[1] = (bf16_t)((a.y - mu) * rv * g0.y + b0.y);
  o8[2] = (bf16_t)((a.z - mu) * rv * g0.z + b0.z);
  o8[3] = (bf16_t)((a.w - mu) * rv * g0.w + b0.w);
  o8[4] = (bf16_t)((c.x - mu) * rv * g1.x + b1.x);
  o8[5] = (bf16_t)((c.y - mu) * rv * g1.y + b1.y);
  o8[6] = (bf16_t)((c.z - mu) * rv * g1.z + b1.z);
  o8[7] = (bf16_t)((c.w - mu) * rv * g1.w + b1.w);
  *(bf16x8*)(out + (size_t)row * DM + lane * 8) = o8;
}

// ------------- Fused weight prep: all 6 transposes in one launch ------------
__global__ __launch_bounds__(256)
void prep_weights(const float* __restrict__ Wq, const float* __restrict__ Wk,
                  const float* __restrict__ Wv, const float* __restrict__ Wo,
                  const float* __restrict__ W1, const float* __restrict__ W2,
                  bf16_t* __restrict__ WqkvT, bf16_t* __restrict__ WoT,
                  bf16_t* __restrict__ W1T, bf16_t* __restrict__ W2T)
{
  const int bid = blockIdx.x;
  const float* src; bf16_t* dst; int Kd, Nd, n0, k0;
  if (bid < 768) {
    int seg = bid >> 8, t = bid & 255;
    src = (seg == 0) ? Wq : (seg == 1) ? Wk : Wv;
    dst = WqkvT + (size_t)seg * 512 * 512;
    Kd = 512; Nd = 512; n0 = (t & 15) * 32; k0 = (t >> 4) * 32;
  } else if (bid < 1024) {
    int t = bid - 768; src = Wo; dst = WoT;
    Kd = 512; Nd = 512; n0 = (t & 15) * 32; k0 = (t >> 4) * 32;
  } else if (bid < 2048) {
    int t = bid - 1024; src = W1; dst = W1T;
    Kd = 512; Nd = 2048; n0 = (t & 63) * 32; k0 = (t >> 6) * 32;
  } else {
    int t = bid - 2048; src = W2; dst = W2T;
    Kd = 2048; Nd = 512; n0 = (t & 15) * 32; k0 = (t >> 4) * 32;
  }
  __shared__ float tile[32][33];
  const int tx = threadIdx.x & 31, ty = threadIdx.x >> 5;
#pragma unroll
  for (int i = 0; i < 32; i += 8)
    tile[ty + i][tx] = src[(size_t)(k0 + ty + i) * Nd + n0 + tx];
  __syncthreads();
#pragma unroll
  for (int i = 0; i < 32; i += 8)
    dst[(size_t)(n0 + ty + i) * Kd + k0 + tx] = (bf16_t)tile[tx][ty + i];
}

// ---------------- GEMM: C[M,N] = A[M,K] * Bt[N,K]^T, bf16 MFMA --------------
// Tile = (32*MI) x (32*NJ), BK=64, 4 waves in 2x2; wave computes MI x NJ
// 16x16 output blocks. Staging: linear LDS dest, source chunk XOR row&7.
// EPI: 2 = f32 gelu(acc+bias)+res; 3 = bf16 gelu(acc+bias); 4 = f32 acc+bias+res
//      5 = fused-QKV epilogue (q scaled, k row-major, v transposed+sigma-permuted)
template <int MI, int NJ, int EPI>
__global__ __launch_bounds__(256)
void gemm_bt(const bf16_t* __restrict__ A, const bf16_t* __restrict__ Bt,
             const int M, const int N, const int K,
             const float* __restrict__ bias, const float* __restrict__ res,
             bf16_t* __restrict__ outb, float* __restrict__ outf,
             bf16_t* __restrict__ out2, bf16_t* __restrict__ out3, const int ldt)
{
  constexpr int MTILE = 32 * MI, NTILE = 32 * NJ;
  constexpr int ACOPY = MTILE / 32;    // staging instrs per thread (BK=64)
  constexpr int BCOPY = NTILE / 32;
  __shared__ __align__(16) bf16_t lA[MTILE * 64];
  __shared__ __align__(16) bf16_t lB[NTILE * 64];
  const int tid = threadIdx.x;
  const int wave = tid >> 6, lane = tid & 63;
  const int wm = wave & 1, wn = wave >> 1;
  const int quad = lane >> 4, l16 = lane & 15;

  int srA[ACOPY > BCOPY ? ACOPY : BCOPY], scA[ACOPY > BCOPY ? ACOPY : BCOPY];
#pragma unroll
  for (int i = 0; i < (ACOPY > BCOPY ? ACOPY : BCOPY); ++i) {
    int flat = tid + 256 * i;
    int r = flat >> 3, ch = flat & 7;
    srA[i] = r;
    scA[i] = (ch ^ (r & 7)) * 8;       // source-side swizzle, dest stays linear
  }
  const bf16_t* Ab = A + (size_t)(blockIdx.x * MTILE) * K;
  const bf16_t* Bb = Bt + (size_t)(blockIdx.y * NTILE) * K;

  const floatx4 vzero = {0.f, 0.f, 0.f, 0.f};
  floatx4 acc[MI][NJ];
#pragma unroll
  for (int i = 0; i < MI; ++i)
#pragma unroll
    for (int j = 0; j < NJ; ++j) acc[i][j] = vzero;

  for (int k0 = 0; k0 < K; k0 += 64) {
    __syncthreads();
#pragma unroll
    for (int i = 0; i < ACOPY; ++i)
      async_copy16(Ab + (size_t)srA[i] * K + k0 + scA[i], lA + (tid + 256 * i) * 8);
#pragma unroll
    for (int i = 0; i < BCOPY; ++i)
      async_copy16(Bb + (size_t)srA[i] * K + k0 + scA[i], lB + (tid + 256 * i) * 8);
    __syncthreads();
#pragma unroll
    for (int c = 0; c < 2; ++c) {
      bf16x8 af[MI], bfv[NJ];
#pragma unroll
      for (int i = 0; i < MI; ++i)
        af[i] = *(const bf16x8*)(lA + (wm * 16 * MI + i * 16 + l16) * 64
                                 + (((c * 4 + quad) ^ (l16 & 7)) * 8));
#pragma unroll
      for (int j = 0; j < NJ; ++j)
        bfv[j] = *(const bf16x8*)(lB + (wn * 16 * NJ + j * 16 + l16) * 64
                                  + (((c * 4 + quad) ^ (l16 & 7)) * 8));
#pragma unroll
      for (int i = 0; i < MI; ++i)
#pragma unroll
        for (int j = 0; j < NJ; ++j)
          acc[i][j] = __builtin_amdgcn_mfma_f32_16x16x32_bf16(af[i], bfv[j], acc[i][j], 0, 0, 0);
    }
  }

  const int m00 = blockIdx.x * MTILE + wm * 16 * MI;
  const int n00 = blockIdx.y * NTILE + wn * 16 * NJ;
#pragma unroll
  for (int i = 0; i < MI; ++i) {
#pragma unroll
    for (int j = 0; j < NJ; ++j) {
      const int m0 = m00 + i * 16 + quad * 4;     // C/D: row=quad*4+reg, col=l16
      const int n  = n00 + j * 16 + l16;
      floatx4 v = acc[i][j];
      if (EPI == 2) {
        const float bb = bias[n];
#pragma unroll
        for (int r = 0; r < 4; ++r)
          outf[(size_t)(m0 + r) * N + n] = gelu_f(v[r] + bb) + res[(size_t)(m0 + r) * N + n];
      } else if (EPI == 3) {
        const float bb = bias[n];
#pragma unroll
        for (int r = 0; r < 4; ++r)
          outb[(size_t)(m0 + r) * N + n] = (bf16_t)gelu_f(v[r] + bb);
      } else if (EPI == 4) {
        const float bb = bias[n];
#pragma unroll
        for (int r = 0; r < 4; ++r)
          outf[(size_t)(m0 + r) * N + n] = v[r] + bb + res[(size_t)(m0 + r) * N + n];
      } else { // EPI 5: fused QKV
        const int seg = blockIdx.y >> 2;          // 0=Q 1=K 2=V (uniform per block)
        if (seg == 0) {
          // fold softmax scale (1/sqrt(64) * log2(e)) into Q, exact in fp32
#pragma unroll
          for (int r = 0; r < 4; ++r)
            outb[(size_t)(m0 + r) * 512 + n] = (bf16_t)(v[r] * 0.180336879f);
        } else if (seg == 1) {
#pragma unroll
          for (int r = 0; r < 4; ++r) out2[(size_t)(m0 + r) * 512 + (n - 512)] = (bf16_t)v[r];
        } else {
          // sigma-permute keys within 32-groups so attn PV A-frags are contiguous:
          // stored p = (o&3) + ((o>>2)&3)*8 + ((o>>4)&1)*4, o = m0&31 (mult of 4)
          const int o = m0 & 31;
          const int p0 = (m0 & ~31) + ((o >> 2) & 3) * 8 + ((o >> 4) << 2);
          bf16x4 pk = {(bf16_t)v[0], (bf16_t)v[1], (bf16_t)v[2], (bf16_t)v[3]};
          *(bf16x4*)(out3 + (size_t)(n - 1024) * ldt + p0) = pk;
        }
      }
    }
  }
}

// ---------------- Flash attention: Q-tile 128, 4 waves x 32 q-rows ----------
// grid (S/128, H, B) = 512 blocks (2/CU, 8 waves/CU); LDS 32 KB (K 16 + V 16).
// S^T = mfma(K-frag, Q-frag): C-layout rows=keys (quad*4+r), cols=qrow (l16).
// kappa-permuted K=32 PV: B-operand = concat of two exp2'd S^T C-regs;
// sigma-permuted V^T makes each PV A-frag one contiguous b128 read.
// Denominator: per-lane f32 partial sums (linear!) + quad shuffle-reduce at end.
__global__ __launch_bounds__(256, 2)
void attn_kernel(const bf16_t* __restrict__ qm, const bf16_t* __restrict__ km,
                 const bf16_t* __restrict__ vtm, const int* __restrict__ mask,
                 bf16_t* __restrict__ ctx)
{
  const int b = blockIdx.z, h = blockIdx.y;
  const int q0 = blockIdx.x * 128;
  const int tid = threadIdx.x;
  const int wave = tid >> 6, lane = tid & 63;
  const int quad = lane >> 4, l16 = lane & 15;

  __shared__ __align__(16) bf16_t lK[128 * DHD];      // [key][dh]          16 KB
  __shared__ __align__(16) bf16_t lV[DHD * 128];      // [dh][stored key]   16 KB
  __shared__ int sclean[4];

  const int* maskb = mask + b * SS;

  // ---- block-level mask pre-check: umin over all 4096 ints ----
  unsigned um = 0xFFFFFFFFu;
#pragma unroll
  for (int i = 0; i < 4; ++i) {
    int4 m = *(const int4*)(maskb + tid * 16 + i * 4);
    um = min(um, min(min((unsigned)m.x, (unsigned)m.y), min((unsigned)m.z, (unsigned)m.w)));
  }
#pragma unroll
  for (int o = 1; o < 64; o <<= 1) um = min(um, (unsigned)__shfl_xor((int)um, o));
  if (lane == 0) sclean[wave] = (int)um;
  __syncthreads();
  const bool clean = (min(min((unsigned)sclean[0], (unsigned)sclean[1]),
                          min((unsigned)sclean[2], (unsigned)sclean[3])) != 0u);

  const size_t qrow0 = (size_t)b * SS + q0;
  // Q as B-operand frags (n=qrow=l16, k=dh=quad*8+t), pre-scaled by softmax factor
  bf16x8 qa[2][2];
#pragma unroll
  for (int mb = 0; mb < 2; ++mb)
#pragma unroll
    for (int cc = 0; cc < 2; ++cc)
      qa[mb][cc] = *(const bf16x8*)(qm + (qrow0 + wave * 32 + mb * 16 + l16) * DM
                                    + h * DHD + cc * 32 + quad * 8);

  const floatx4 vzero = {0.f, 0.f, 0.f, 0.f};
  floatx4 cacc[2][4];
  float lsum[2] = {0.f, 0.f};
#pragma unroll
  for (int mb = 0; mb < 2; ++mb)
#pragma unroll
    for (int nb = 0; nb < 4; ++nb) cacc[mb][nb] = vzero;

  const bf16_t* Kb = km + (size_t)b * SS * DM + h * DHD;
  const bf16_t* Vb = vtm + (size_t)(h * DHD) * MT + (size_t)b * SS;

  for (int s0 = 0; s0 < SS; s0 += 128) {
    __syncthreads();
#pragma unroll
    for (int i = 0; i < 4; ++i) {
      int p = tid + 256 * i;
      int key = p >> 3;
      int cs = (p & 7) ^ (key & 7);
      async_copy16(Kb + (size_t)(s0 + key) * DM + cs * 8, lK + p * 8);
      int dh = p >> 4;
      int cs2 = (p & 15) ^ (dh & 7);
      async_copy16(Vb + (size_t)dh * MT + s0 + cs2 * 8, lV + p * 8);
    }
    __syncthreads();

    // ---- per 32-key chunk: S^T (2 key-blocks x 2 q-groups) -> exp2 -> PV ----
#pragma unroll
    for (int c = 0; c < 4; ++c) {
      floatx4 sa[2], sb[2];
      sa[0] = vzero; sa[1] = vzero; sb[0] = vzero; sb[1] = vzero;
#pragma unroll
      for (int cc = 0; cc < 2; ++cc) {
        const int ko = ((cc * 4 + quad) ^ (l16 & 7)) * 8;
        bf16x8 kf0 = *(const bf16x8*)(lK + (c * 32 + l16) * 64 + ko);
        bf16x8 kf1 = *(const bf16x8*)(lK + (c * 32 + 16 + l16) * 64 + ko);
#pragma unroll
        for (int mb = 0; mb < 2; ++mb) {
          sa[mb] = __builtin_amdgcn_mfma_f32_16x16x32_bf16(kf0, qa[mb][cc], sa[mb], 0, 0, 0);
          sb[mb] = __builtin_amdgcn_mfma_f32_16x16x32_bf16(kf1, qa[mb][cc], sb[mb], 0, 0, 0);
        }
      }

      if (!clean) {   // rare path: -inf where mask==0 (keys quad*4+r within block)
        const int4 m0 = *(const int4*)(maskb + s0 + c * 32 + quad * 4);
        const int4 m1 = *(const int4*)(maskb + s0 + c * 32 + 16 + quad * 4);
#pragma unroll
        for (int mb = 0; mb < 2; ++mb) {
          if (m0.x == 0) sa[mb][0] = -1e30f;
          if (m0.y == 0) sa[mb][1] = -1e30f;
          if (m0.z == 0) sa[mb][2] = -1e30f;
          if (m0.w == 0) sa[mb][3] = -1e30f;
          if (m1.x == 0) sb[mb][0] = -1e30f;
          if (m1.y == 0) sb[mb][1] = -1e30f;
          if (m1.z == 0) sb[mb][2] = -1e30f;
          if (m1.w == 0) sb[mb][3] = -1e30f;
        }
      }

      bf16x8 pf[2];
#pragma unroll
      for (int mb = 0; mb < 2; ++mb) {
        float e0 = fast_exp2(sa[mb][0]), e1 = fast_exp2(sa[mb][1]);
        float e2 = fast_exp2(sa[mb][2]), e3 = fast_exp2(sa[mb][3]);
        float e4 = fast_exp2(sb[mb][0]), e5 = fast_exp2(sb[mb][1]);
        float e6 = fast_exp2(sb[mb][2]), e7 = fast_exp2(sb[mb][3]);
        lsum[mb] += ((e0 + e1) + (e2 + e3)) + ((e4 + e5) + (e6 + e7));
        pf[mb][0] = (bf16_t)e0; pf[mb][1] = (bf16_t)e1;
        pf[mb][2] = (bf16_t)e2; pf[mb][3] = (bf16_t)e3;
        pf[mb][4] = (bf16_t)e4; pf[mb][5] = (bf16_t)e5;
        pf[mb][6] = (bf16_t)e6; pf[mb][7] = (bf16_t)e7;
      }
      const int ch = (c * 4 + quad) ^ (l16 & 7);
#pragma unroll
      for (int nb = 0; nb < 4; ++nb) {
        bf16x8 av = *(const bf16x8*)(lV + (nb * 16 + l16) * 128 + ch * 8);
        cacc[0][nb] = __builtin_amdgcn_mfma_f32_16x16x32_bf16(av, pf[0], cacc[0][nb], 0, 0, 0);
        cacc[1][nb] = __builtin_amdgcn_mfma_f32_16x16x32_bf16(av, pf[1], cacc[1][nb], 0, 0, 0);
      }
    }
  }

  // ---- epilogue: O^T cols=qrow=l16, rows=dh=nb*16+quad*4+r -> 8B stores ----
#pragma unroll
  for (int mb = 0; mb < 2; ++mb) {
    float tot = lsum[mb];
    tot += __shfl_xor(tot, 16);
    tot += __shfl_xor(tot, 32);       // sum across the 4 quad-lanes of this qrow
    const float inv = 1.0f / tot;
    const size_t qrow = qrow0 + wave * 32 + mb * 16 + l16;
#pragma unroll
    for (int nb = 0; nb < 4; ++nb) {
      bf16x4 o = {(bf16_t)(cacc[mb][nb][0] * inv), (bf16_t)(cacc[mb][nb][1] * inv),
                  (bf16_t)(cacc[mb][nb][2] * inv), (bf16_t)(cacc[mb][nb][3] * inv)};
      *(bf16x4*)(ctx + qrow * DM + h * DHD + nb * 16 + quad * 4) = o;
    }
  }
}

// ---------------------------------------------------------------------------
extern "C" void kernel_launch(void* const* d_in, const int* in_sizes, int n_in,
                              void* d_out, int out_size, void* d_ws, size_t ws_size,
                              hipStream_t stream)
{
  (void)in_sizes; (void)n_in; (void)out_size; (void)ws_size;
  const float* reaction = (const float*)d_in[0];
  const int*   mask     = (const int*)d_in[1];
  const float* Wq = (const float*)d_in[2];
  const float* Wk = (const float*)d_in[3];
  const float* Wv = (const float*)d_in[4];
  const float* Wo = (const float*)d_in[5];
  const float* bo = (const float*)d_in[6];
  const float* W1 = (const float*)d_in[7];
  const float* b1 = (const float*)d_in[8];
  const float* W2 = (const float*)d_in[9];
  const float* b2 = (const float*)d_in[10];
  const float* g_sa = (const float*)d_in[11];
  const float* b_sa = (const float*)d_in[12];
  const float* g_ff = (const float*)d_in[13];
  const float* b_ff = (const float*)d_in[14];
  float* out = (float*)d_out;

  char* ws = (char*)d_ws;
  size_t off = 0;
  auto take = [&](size_t bytes) -> char* {
    char* p = ws + off;
    off += (bytes + 255) & ~(size_t)255;
    return p;
  };

  bf16_t* xln   = (bf16_t*)take((size_t)MT * DM * 2);       // LN1 out; reused as LN2 out
  bf16_t* WqkvT = (bf16_t*)take((size_t)3 * DM * DM * 2);   // [1536][512]
  bf16_t* WoT   = (bf16_t*)take((size_t)DM * DM * 2);
  bf16_t* W1T   = (bf16_t*)take((size_t)FFD * DM * 2);
  bf16_t* W2T   = (bf16_t*)take((size_t)DM * FFD * 2);
  bf16_t* qb    = (bf16_t*)take((size_t)MT * DM * 2);       // qb..ctx contiguous 32MB,
  bf16_t* kb    = (bf16_t*)take((size_t)MT * DM * 2);       // reused as FFN hidden h
  bf16_t* vtb   = (bf16_t*)take((size_t)DM * MT * 2);       // V transposed [D, M], sigma-permuted
  bf16_t* ctx   = (bf16_t*)take((size_t)MT * DM * 2);
  float*  x2    = (float*)take((size_t)MT * DM * 4);
  bf16_t* yb    = xln;
  bf16_t* hb    = qb;   // 8192*2048 bf16 = 32MB over qb/kb/vtb/ctx (all dead by then)

  ln_kernel<<<MT / 4, 256, 0, stream>>>(reaction, g_sa, b_sa, xln);
  prep_weights<<<3072, 256, 0, stream>>>(Wq, Wk, Wv, Wo, W1, W2, WqkvT, WoT, W1T, W2T);

  // Fused QKV projection (Q pre-scaled, V stored transposed + sigma-permuted)
  gemm_bt<4, 4, 5><<<dim3(64, 12), 256, 0, stream>>>(xln, WqkvT, MT, 3 * DM, DM,
                                                     nullptr, nullptr, qb, nullptr, kb, vtb, MT);

  attn_kernel<<<dim3(SS / 128, HN, BB), 256, 0, stream>>>(qb, kb, vtb, mask, ctx);

  // Output projection + GELU + residual -> x2 (fp32); 128x64 tiles, 2 blocks/CU
  gemm_bt<4, 2, 2><<<dim3(64, 8), 256, 0, stream>>>(ctx, WoT, MT, DM, DM,
                                                    bo, reaction, nullptr, x2, nullptr, nullptr, 0);

  ln_kernel<<<MT / 4, 256, 0, stream>>>(x2, g_ff, b_ff, yb);
  gemm_bt<4, 4, 3><<<dim3(64, 16), 256, 0, stream>>>(yb, W1T, MT, FFD, DM,
                                                     b1, nullptr, hb, nullptr, nullptr, nullptr, 0);
  gemm_bt<4, 2, 4><<<dim3(64, 8), 256, 0, stream>>>(hb, W2T, MT, DM, FFD,
                                                    b2, x2, nullptr, out, nullptr, nullptr, 0);
}